// Round 1
// baseline (608.622 us; speedup 1.0000x reference)
//
#include <hip/hip_runtime.h>

#define BB 1024
#define TT 256
#define EE 384
#define HH 64

typedef float  f32x4  __attribute__((ext_vector_type(4)));
typedef short  short8 __attribute__((ext_vector_type(8)));
typedef unsigned short us4 __attribute__((ext_vector_type(4)));

// fp32 -> bf16 round-to-nearest-even
__device__ __forceinline__ unsigned short f2bf(float f) {
    unsigned int u = __float_as_uint(f);
    u += 0x7FFFu + ((u >> 16) & 1u);
    return (unsigned short)(u >> 16);
}

__device__ __forceinline__ void gl_lds16(const void* g, void* l) {
    __builtin_amdgcn_global_load_lds(
        (const __attribute__((address_space(1))) unsigned int*)g,
        (__attribute__((address_space(3))) unsigned int*)l, 16, 0, 0);
}

// ============================ SPLIT PATH ============================

// Wt2: per-kt-sliced, XOR-swizzled LDS image of [Wq*scale | Wk | Wv]^T.
// Element (n, k = kt*32 + c*8 + e) stored at  kt*6144 + n*32 + (c^(n&3))*8 + e.
__global__ void prep2_kernel(const float* __restrict__ Wq, const float* __restrict__ Wk,
                             const float* __restrict__ Wv, unsigned short* __restrict__ Wt2) {
    int i = blockIdx.x * 256 + threadIdx.x;     // 12*6144 = 73728 = 288*256
    if (i >= 12 * 6144) return;
    int kt = i / 6144;
    int r1 = i - kt * 6144;
    int n  = r1 >> 5;
    int r2 = r1 & 31;
    int sc = r2 >> 3, e = r2 & 7;
    int c  = sc ^ (n & 3);
    int k  = kt * 32 + c * 8 + e;
    float v;
    if (n < 64)       v = Wq[k * HH + n] * 0.18033688011112042f;   // 0.125 * log2(e)
    else if (n < 128) v = Wk[k * HH + (n - 64)];
    else              v = Wv[k * HH + (n - 128)];
    Wt2[i] = f2bf(v);
}

// QKV projection. 256 thr / 4 waves; 128 rows per block; grid 2048.
// Double-buffered 2-phase staging (T3 minimum recipe): stage kt+1 into buf^1,
// compute kt from buf, ONE __syncthreads (vmcnt(0)+barrier) per kt. Loads overlap
// fragment reads + 24 MFMA + cvt; barrier count 24 -> 13.
// LDS 56 KB -> still 2 blocks/CU.
// Outputs (bf16): Qimg plain [b][t][h]; Kimg [b][t][hchunk^(t&7)]; Vimg [b][h][tchunk^(h&7)].
__global__ __launch_bounds__(256, 2) void qkv_kernel(const float* __restrict__ x,
                                                     const unsigned short* __restrict__ Wt2,
                                                     unsigned short* __restrict__ Qimg,
                                                     unsigned short* __restrict__ Kimg,
                                                     unsigned short* __restrict__ Vimg) {
    __shared__ __align__(16) float          xs[2][128 * 32];   // 2 x 16 KB
    __shared__ __align__(16) unsigned short wts[2][6144];      // 2 x 12 KB

    const int tid  = threadIdx.x;
    const int lane = tid & 63;
    const int w    = tid >> 6;          // wave 0..3
    const int g    = lane >> 4;
    const int mr   = lane & 15;
    const int m7   = mr & 7;
    const int m3   = mr & 3;
    const long rows0 = (long)blockIdx.x * 128;

    f32x4 acc[2][12];
#pragma unroll
    for (int ti = 0; ti < 2; ++ti)
#pragma unroll
        for (int nt = 0; nt < 12; ++nt) acc[ti][nt] = (f32x4){0.f, 0.f, 0.f, 0.f};

    const int swb = (g ^ m3) << 3;      // B-frag swizzled chunk offset (halfwords)

    // stage k-slice kt into buffer sel (coalesced, source-side XOR swizzle)
    auto stage = [&](int kt, int sel) {
#pragma unroll
        for (int j = 0; j < 4; ++j) {
            int chunk = j * 256 + tid;
            int r = chunk >> 3, c = chunk & 7;
            const float* src = x + (rows0 + r) * EE + kt * 32 + ((c ^ (r & 7)) << 2);
            gl_lds16(src, xs[sel] + (j * 256 + w * 64) * 4);
        }
#pragma unroll
        for (int j = 0; j < 3; ++j) {
            int ch = j * 256 + tid;
            gl_lds16(Wt2 + kt * 6144 + ch * 8, wts[sel] + (j * 256 + w * 64) * 8);
        }
    };

    stage(0, 0);
    __syncthreads();

    for (int kt = 0; kt < 12; ++kt) {
        const int cur = kt & 1;
        if (kt + 1 < 12) stage(kt + 1, cur ^ 1);   // prefetch: overlaps compute below

        short8 afr[2];
#pragma unroll
        for (int ti = 0; ti < 2; ++ti) {
            const int lr = w * 32 + ti * 16 + mr;
            const float* base = xs[cur] + lr * 32;
            f32x4 lo = *(const f32x4*)(base + (((2 * g)     ^ m7) << 2));
            f32x4 hi = *(const f32x4*)(base + (((2 * g + 1) ^ m7) << 2));
            union { short8 v; unsigned short u[8]; } cv;
            cv.u[0] = f2bf(lo.x); cv.u[1] = f2bf(lo.y); cv.u[2] = f2bf(lo.z); cv.u[3] = f2bf(lo.w);
            cv.u[4] = f2bf(hi.x); cv.u[5] = f2bf(hi.y); cv.u[6] = f2bf(hi.z); cv.u[7] = f2bf(hi.w);
            afr[ti] = cv.v;
        }
#pragma unroll
        for (int nt = 0; nt < 12; ++nt) {
            short8 bfr = *(const short8*)(wts[cur] + (nt * 16 + mr) * 32 + swb);
            acc[0][nt] = __builtin_amdgcn_mfma_f32_16x16x32_bf16(afr[0], bfr, acc[0][nt], 0, 0, 0);
            acc[1][nt] = __builtin_amdgcn_mfma_f32_16x16x32_bf16(afr[1], bfr, acc[1][nt], 0, 0, 0);
        }
        __syncthreads();   // drains prefetch (had whole compute to progress) + LDS WAR
    }

    // epilogue -> bf16 images
    const int b  = blockIdx.x >> 1;
    const int t0 = (blockIdx.x & 1) * 128;
    unsigned short* Qb = Qimg + (size_t)b * 16384;
    unsigned short* Kb = Kimg + (size_t)b * 16384;
    unsigned short* Vb = Vimg + (size_t)b * 16384;

#pragma unroll
    for (int ti = 0; ti < 2; ++ti) {
        const int tbase = t0 + w * 32 + ti * 16;
#pragma unroll
        for (int nt = 0; nt < 12; ++nt) {
            f32x4 v = acc[ti][nt];
            if (nt < 4) {
                const int h = nt * 16 + mr;
#pragma unroll
                for (int r = 0; r < 4; ++r)
                    Qb[(tbase + g * 4 + r) * 64 + h] = f2bf(v[r]);
            } else if (nt < 8) {
                const int hc = (nt - 4) * 2 + (mr >> 3);
#pragma unroll
                for (int r = 0; r < 4; ++r) {
                    const int t = tbase + g * 4 + r;
                    Kb[t * 64 + ((hc ^ (t & 7)) << 3) + m7] = f2bf(v[r]);
                }
            } else {
                const int h  = (nt - 8) * 16 + mr;
                const int tq = tbase + g * 4;
                const int sw = (tq >> 3) ^ m7;
                us4 pk;
                pk.x = f2bf(v[0]); pk.y = f2bf(v[1]); pk.z = f2bf(v[2]); pk.w = f2bf(v[3]);
                *(us4*)(Vb + h * 256 + sw * 8 + (tq & 7)) = pk;
            }
        }
    }
}

// Flash attention. 512 thr / 8 waves, one block per batch, grid 1024.
// LDS = 80 KB exactly (swizzled, pad-free) and <=128 regs -> 2 blocks/CU.
// Balanced wave->row mapping (a = p ? 15-w : w): every wave owns exactly 5
// causal chunks (was 4/6 split -> critical path 6). setprio(1) around MFMA
// clusters (waves run barrier-free and phase-diverse -> T5 regime).
__global__ __launch_bounds__(512, 4) void attn2_kernel(const unsigned short* __restrict__ Qimg,
                                                       const unsigned short* __restrict__ Kimg,
                                                       const unsigned short* __restrict__ Vimg,
                                                       float* __restrict__ out) {
    __shared__ __align__(16) unsigned short Ks[16384];   // 32 KB  K[t][chunk^(t&7)]
    __shared__ __align__(16) unsigned short Vs[16384];   // 32 KB  V^T[h][chunk^(h&7)]
    __shared__ __align__(16) unsigned short Ps[8192];    // 16 KB  per-wave P 16x64 swizzled

    const int tid  = threadIdx.x;
    const int lane = tid & 63;
    const int w    = tid >> 6;          // wave 0..7
    const int g    = lane >> 4;
    const int mr   = lane & 15;
    const int m7   = mr & 7;
    const int b    = blockIdx.x;

    const unsigned short* Qb = Qimg + (size_t)b * 16384;
    const unsigned short* Kb = Kimg + (size_t)b * 16384;
    const unsigned short* Vb = Vimg + (size_t)b * 16384;

    // Q fragments straight from global (4 scattered 16B loads; overlap with staging)
    short8 qfr[2][2];
#pragma unroll
    for (int p = 0; p < 2; ++p) {
        const int a0 = p ? (15 - w) : w;
        const int t0 = a0 * 16;
#pragma unroll
        for (int kt = 0; kt < 2; ++kt)
            qfr[p][kt] = *(const short8*)(Qb + (t0 + mr) * 64 + kt * 32 + g * 8);
    }

    // stage K,V (contiguous LDS images -> perfectly coalesced)
#pragma unroll
    for (int j = 0; j < 4; ++j) {
        int ch = j * 512 + tid;
        gl_lds16(Kb + ch * 8, Ks + (j * 512 + w * 64) * 8);
    }
#pragma unroll
    for (int j = 0; j < 4; ++j) {
        int ch = j * 512 + tid;
        gl_lds16(Vb + ch * 8, Vs + (j * 512 + w * 64) * 8);
    }
    __syncthreads();

    const int swv0 = ((0 * 4 + g) ^ m7) << 3;   // swizzled chunk offsets (halfwords)
    const int swv1 = ((1 * 4 + g) ^ m7) << 3;
    unsigned short* pw = Ps + w * 1024;

    short8 ones;
#pragma unroll
    for (int i = 0; i < 8; ++i) ones[i] = (short)0x3F80;   // bf16 1.0

#pragma unroll
    for (int p = 0; p < 2; ++p) {
        const int a   = p ? (15 - w) : w;    // balanced: each wave = 5 chunks total
        const int r0  = a * 16;
        const int nch = (a >> 2) + 1;

        f32x4 o[4];
        f32x4 ls = (f32x4){0.f, 0.f, 0.f, 0.f};
        float mrun[4];
#pragma unroll
        for (int i = 0; i < 4; ++i) { o[i] = (f32x4){0.f, 0.f, 0.f, 0.f}; mrun[i] = -3.0e38f; }

        for (int j = 0; j < nch; ++j) {
            // S = Q K^T   (scale*log2e folded into Q)
            f32x4 s[4];
#pragma unroll
            for (int nt = 0; nt < 4; ++nt) s[nt] = (f32x4){0.f, 0.f, 0.f, 0.f};
            __builtin_amdgcn_s_setprio(1);
#pragma unroll
            for (int kt = 0; kt < 2; ++kt) {
                const short8 qf = qfr[p][kt];
                const int swv = kt ? swv1 : swv0;
#pragma unroll
                for (int nt = 0; nt < 4; ++nt) {
                    short8 kf = *(const short8*)(Ks + (j * 64 + nt * 16 + mr) * 64 + swv);
                    s[nt] = __builtin_amdgcn_mfma_f32_16x16x32_bf16(qf, kf, s[nt], 0, 0, 0);
                }
            }
            __builtin_amdgcn_s_setprio(0);
            // causal mask: only the last chunk contains the diagonal
            if (j == nch - 1) {
#pragma unroll
                for (int nt = 0; nt < 4; ++nt) {
                    const int key = j * 64 + nt * 16 + mr;
#pragma unroll
                    for (int r = 0; r < 4; ++r)
                        if (key > r0 + g * 4 + r) s[nt][r] = -3.0e38f;
                }
            }
            // row max (4 regs + 16-lane shuffle tree)
            float cm[4], al[4];
#pragma unroll
            for (int r = 0; r < 4; ++r) {
                cm[r] = fmaxf(fmaxf(s[0][r], s[1][r]), fmaxf(s[2][r], s[3][r]));
                cm[r] = fmaxf(cm[r], __shfl_xor(cm[r], 1, 64));
                cm[r] = fmaxf(cm[r], __shfl_xor(cm[r], 2, 64));
                cm[r] = fmaxf(cm[r], __shfl_xor(cm[r], 4, 64));
                cm[r] = fmaxf(cm[r], __shfl_xor(cm[r], 8, 64));
                float mn = fmaxf(mrun[r], cm[r]);
                al[r] = exp2f(mrun[r] - mn);
                mrun[r] = mn;
            }
            // P = exp2(S - m) -> bf16 -> swizzled per-wave scratch (C-layout writes)
#pragma unroll
            for (int nt = 0; nt < 4; ++nt) {
#pragma unroll
                for (int r = 0; r < 4; ++r) {
                    const int lr = g * 4 + r;
                    const int sw = (nt * 2 + (mr >> 3)) ^ (lr & 7);
                    pw[lr * 64 + (sw << 3) + m7] = f2bf(exp2f(s[nt][r] - mrun[r]));
                }
            }
            // rescale, then O += P V and l += P*1 (ones-column MFMA replaces shuffle sums)
#pragma unroll
            for (int hn = 0; hn < 4; ++hn)
#pragma unroll
                for (int r = 0; r < 4; ++r) o[hn][r] *= al[r];
#pragma unroll
            for (int r = 0; r < 4; ++r) ls[r] *= al[r];
            __builtin_amdgcn_s_setprio(1);
#pragma unroll
            for (int kt = 0; kt < 2; ++kt) {
                const int swv = kt ? swv1 : swv0;
                short8 pf = *(const short8*)(pw + mr * 64 + swv);
#pragma unroll
                for (int hn = 0; hn < 4; ++hn) {
                    short8 vf = *(const short8*)(Vs + (hn * 16 + mr) * 256 + j * 64 + swv);
                    o[hn] = __builtin_amdgcn_mfma_f32_16x16x32_bf16(pf, vf, o[hn], 0, 0, 0);
                }
                ls = __builtin_amdgcn_mfma_f32_16x16x32_bf16(pf, ones, ls, 0, 0, 0);
            }
            __builtin_amdgcn_s_setprio(0);
        }
        // normalize + store
        float* ob = out + ((size_t)b * TT + r0) * HH;
#pragma unroll
        for (int r = 0; r < 4; ++r) {
            const float inv = 1.0f / ls[r];
#pragma unroll
            for (int hn = 0; hn < 4; ++hn)
                ob[(g * 4 + r) * HH + hn * 16 + mr] = o[hn][r] * inv;
        }
    }
}

// ============================ FALLBACK PATH (R1, proven) ============================

__global__ void prep_kernel(const float* __restrict__ Wq, const float* __restrict__ Wk,
                            const float* __restrict__ Wv, unsigned short* __restrict__ Wt) {
    int i = blockIdx.x * 256 + threadIdx.x;
    if (i >= 192 * EE) return;
    int n = i / EE, k = i - n * EE;
    float v;
    if (n < 64)       v = Wq[k * HH + n] * 0.18033688011112042f;
    else if (n < 128) v = Wk[k * HH + (n - 64)];
    else              v = Wv[k * HH + (n - 128)];
    Wt[i] = f2bf(v);
}

__global__ __launch_bounds__(512, 2) void attn_kernel(const float* __restrict__ x,
                                                      const unsigned short* __restrict__ Wt,
                                                      float* __restrict__ out) {
    __shared__ unsigned short Qs[TT * 72];
    __shared__ unsigned short Ksh[TT * 72];
    __shared__ unsigned short Vt[HH * 264];
    __shared__ unsigned short Psc[8 * 1152];

    const int tid  = threadIdx.x;
    const int lane = tid & 63;
    const int w    = tid >> 6;
    const int g    = lane >> 4;
    const int mr   = lane & 15;
    const int b    = blockIdx.x;
    const float* xb = x + (size_t)b * (TT * EE);

    f32x4 acc[2][12];
#pragma unroll
    for (int ti = 0; ti < 2; ++ti)
#pragma unroll
        for (int nt = 0; nt < 12; ++nt) acc[ti][nt] = (f32x4){0.f, 0.f, 0.f, 0.f};

    const int M0a = (2 * w) * 16, M0b = (2 * w + 1) * 16;

    for (int kt = 0; kt < 12; ++kt) {
        const int k0 = kt * 32 + g * 8;
        short8 bfr[12];
#pragma unroll
        for (int nt = 0; nt < 12; ++nt)
            bfr[nt] = *(const short8*)(Wt + (size_t)(nt * 16 + mr) * EE + k0);
        short8 afr[2];
#pragma unroll
        for (int ti = 0; ti < 2; ++ti) {
            const int m0 = ti ? M0b : M0a;
            const float* ap = xb + (size_t)(m0 + mr) * EE + k0;
            f32x4 lo = *(const f32x4*)ap;
            f32x4 hi = *(const f32x4*)(ap + 4);
            union { short8 v; unsigned short u[8]; } cv;
            cv.u[0] = f2bf(lo.x); cv.u[1] = f2bf(lo.y); cv.u[2] = f2bf(lo.z); cv.u[3] = f2bf(lo.w);
            cv.u[4] = f2bf(hi.x); cv.u[5] = f2bf(hi.y); cv.u[6] = f2bf(hi.z); cv.u[7] = f2bf(hi.w);
            afr[ti] = cv.v;
        }
#pragma unroll
        for (int nt = 0; nt < 12; ++nt) {
            acc[0][nt] = __builtin_amdgcn_mfma_f32_16x16x32_bf16(afr[0], bfr[nt], acc[0][nt], 0, 0, 0);
            acc[1][nt] = __builtin_amdgcn_mfma_f32_16x16x32_bf16(afr[1], bfr[nt], acc[1][nt], 0, 0, 0);
        }
    }

#pragma unroll
    for (int ti = 0; ti < 2; ++ti) {
        const int row = (ti ? M0b : M0a) + g * 4;
#pragma unroll
        for (int nt = 0; nt < 12; ++nt) {
            f32x4 v = acc[ti][nt];
            if (nt < 4) {
                const int col = nt * 16 + mr;
#pragma unroll
                for (int r = 0; r < 4; ++r) Qs[(row + r) * 72 + col] = f2bf(v[r]);
            } else if (nt < 8) {
                const int col = (nt - 4) * 16 + mr;
#pragma unroll
                for (int r = 0; r < 4; ++r) Ksh[(row + r) * 72 + col] = f2bf(v[r]);
            } else {
                const int h = (nt - 8) * 16 + mr;
                us4 pk;
                pk.x = f2bf(v[0]); pk.y = f2bf(v[1]); pk.z = f2bf(v[2]); pk.w = f2bf(v[3]);
                *(us4*)(&Vt[h * 264 + row]) = pk;
            }
        }
    }
    __syncthreads();

#pragma unroll
    for (int pass = 0; pass < 2; ++pass) {
        const int a  = pass ? (15 - w) : w;
        const int r0 = a * 16;
        f32x4 o[4];
        float mrun[4], lrun[4];
#pragma unroll
        for (int i = 0; i < 4; ++i) {
            o[i] = (f32x4){0.f, 0.f, 0.f, 0.f};
            mrun[i] = -3.0e38f; lrun[i] = 0.f;
        }
        const int nch = (a >> 2) + 1;
        unsigned short* pwv = Psc + w * 1152;

        for (int j = 0; j < nch; ++j) {
            f32x4 s[4];
#pragma unroll
            for (int nt = 0; nt < 4; ++nt) s[nt] = (f32x4){0.f, 0.f, 0.f, 0.f};
#pragma unroll
            for (int kt = 0; kt < 2; ++kt) {
                short8 qf = *(const short8*)(Qs + (r0 + mr) * 72 + kt * 32 + g * 8);
#pragma unroll
                for (int nt = 0; nt < 4; ++nt) {
                    short8 kf = *(const short8*)(Ksh + (j * 64 + nt * 16 + mr) * 72 + kt * 32 + g * 8);
                    s[nt] = __builtin_amdgcn_mfma_f32_16x16x32_bf16(qf, kf, s[nt], 0, 0, 0);
                }
            }
            if (j * 64 + 63 > r0) {
#pragma unroll
                for (int nt = 0; nt < 4; ++nt) {
                    const int key = j * 64 + nt * 16 + mr;
#pragma unroll
                    for (int r = 0; r < 4; ++r)
                        if (key > r0 + g * 4 + r) s[nt][r] = -3.0e38f;
                }
            }
            float cm[4];
#pragma unroll
            for (int r = 0; r < 4; ++r) {
                cm[r] = fmaxf(fmaxf(s[0][r], s[1][r]), fmaxf(s[2][r], s[3][r]));
                cm[r] = fmaxf(cm[r], __shfl_xor(cm[r], 1, 64));
                cm[r] = fmaxf(cm[r], __shfl_xor(cm[r], 2, 64));
                cm[r] = fmaxf(cm[r], __shfl_xor(cm[r], 4, 64));
                cm[r] = fmaxf(cm[r], __shfl_xor(cm[r], 8, 64));
            }
            float al[4];
#pragma unroll
            for (int r = 0; r < 4; ++r) {
                float mn = fmaxf(mrun[r], cm[r]);
                al[r] = exp2f(mrun[r] - mn);
                mrun[r] = mn;
            }
            float rs[4] = {0.f, 0.f, 0.f, 0.f};
#pragma unroll
            for (int nt = 0; nt < 4; ++nt) {
#pragma unroll
                for (int r = 0; r < 4; ++r) {
                    float pv = exp2f(s[nt][r] - mrun[r]);
                    rs[r] += pv;
                    pwv[(g * 4 + r) * 72 + nt * 16 + mr] = f2bf(pv);
                }
            }
#pragma unroll
            for (int r = 0; r < 4; ++r) {
                rs[r] += __shfl_xor(rs[r], 1, 64);
                rs[r] += __shfl_xor(rs[r], 2, 64);
                rs[r] += __shfl_xor(rs[r], 4, 64);
                rs[r] += __shfl_xor(rs[r], 8, 64);
                lrun[r] = lrun[r] * al[r] + rs[r];
            }
#pragma unroll
            for (int hn = 0; hn < 4; ++hn)
#pragma unroll
                for (int r = 0; r < 4; ++r) o[hn][r] *= al[r];
#pragma unroll
            for (int kt = 0; kt < 2; ++kt) {
                short8 pf = *(const short8*)(pwv + mr * 72 + kt * 32 + g * 8);
#pragma unroll
                for (int hn = 0; hn < 4; ++hn) {
                    short8 vf = *(const short8*)(Vt + (hn * 16 + mr) * 264 + j * 64 + kt * 32 + g * 8);
                    o[hn] = __builtin_amdgcn_mfma_f32_16x16x32_bf16(pf, vf, o[hn], 0, 0, 0);
                }
            }
        }
        float* ob = out + ((size_t)b * TT + r0) * HH;
#pragma unroll
        for (int r = 0; r < 4; ++r) {
            const float inv = 1.0f / lrun[r];
#pragma unroll
            for (int hn = 0; hn < 4; ++hn)
                ob[(g * 4 + r) * HH + hn * 16 + mr] = o[hn][r] * inv;
        }
    }
}

// ============================ launcher ============================

extern "C" void kernel_launch(void* const* d_in, const int* in_sizes, int n_in,
                              void* d_out, int out_size, void* d_ws, size_t ws_size,
                              hipStream_t stream) {
    const float* x  = (const float*)d_in[0];
    const float* Wq = (const float*)d_in[1];
    const float* Wk = (const float*)d_in[2];
    const float* Wv = (const float*)d_in[3];
    float* out = (float*)d_out;

    const size_t img = (size_t)1024 * 16384;            // elements per image (bf16)
    const size_t need = 147456 + 3 * img * 2;           // Wt2 + Q,K,V images  (~96.2 MB)

    if (ws_size >= need) {
        unsigned short* Wt2  = (unsigned short*)d_ws;
        unsigned short* Qimg = (unsigned short*)((char*)d_ws + 147456);
        unsigned short* Kimg = Qimg + img;
        unsigned short* Vimg = Kimg + img;
        prep2_kernel<<<288, 256, 0, stream>>>(Wq, Wk, Wv, Wt2);
        qkv_kernel<<<2048, 256, 0, stream>>>(x, Wt2, Qimg, Kimg, Vimg);
        attn2_kernel<<<1024, 512, 0, stream>>>(Qimg, Kimg, Vimg, out);
    } else {
        unsigned short* Wt = (unsigned short*)d_ws;     // 147456 B (fits: R1 ran with this)
        prep_kernel<<<288, 256, 0, stream>>>(Wq, Wk, Wv, Wt);
        attn_kernel<<<BB, 512, 0, stream>>>(x, Wt, out);
    }
}

// Round 3
// 588.406 us; speedup vs baseline: 1.0344x; 1.0344x over previous
//
#include <hip/hip_runtime.h>

#define BB 1024
#define TT 256
#define EE 384
#define HH 64

typedef float  f32x4  __attribute__((ext_vector_type(4)));
typedef short  short8 __attribute__((ext_vector_type(8)));
typedef unsigned short us4 __attribute__((ext_vector_type(4)));

// fp32 -> bf16 round-to-nearest-even
__device__ __forceinline__ unsigned short f2bf(float f) {
    unsigned int u = __float_as_uint(f);
    u += 0x7FFFu + ((u >> 16) & 1u);
    return (unsigned short)(u >> 16);
}

__device__ __forceinline__ void gl_lds16(const void* g, void* l) {
    __builtin_amdgcn_global_load_lds(
        (const __attribute__((address_space(1))) unsigned int*)g,
        (__attribute__((address_space(3))) unsigned int*)l, 16, 0, 0);
}

// Wt2: per-kt-sliced, XOR-swizzled image of [Wq*scale | Wk | Wv]^T (bf16).
// Element (n, k = kt*32 + c*8 + e) stored at  kt*6144 + n*32 + (c^(n&3))*8 + e.
__global__ void prep2_kernel(const float* __restrict__ Wq, const float* __restrict__ Wk,
                             const float* __restrict__ Wv, unsigned short* __restrict__ Wt2) {
    int i = blockIdx.x * 256 + threadIdx.x;     // 12*6144 = 73728 = 288*256
    if (i >= 12 * 6144) return;
    int kt = i / 6144;
    int r1 = i - kt * 6144;
    int n  = r1 >> 5;
    int r2 = r1 & 31;
    int sc = r2 >> 3, e = r2 & 7;
    int c  = sc ^ (n & 3);
    int k  = kt * 32 + c * 8 + e;
    float v;
    if (n < 64)       v = Wq[k * HH + n] * 0.18033688011112042f;   // 0.125 * log2(e)
    else if (n < 128) v = Wk[k * HH + (n - 64)];
    else              v = Wv[k * HH + (n - 128)];
    Wt2[i] = f2bf(v);
}

// Fused QKV projection + flash attention. One block per batch: 1024 blocks x 512 thr.
// Phase 1: project this batch's 256x384 rows against Wt2 (12 k-steps, gl_lds16-staged,
//   XOR-swizzled LDS). Wave w computes row-tiles {w, 15-w} -> its OWN attention tiles,
//   so Q never leaves registers (fragment-converted via the per-wave P-scratch swizzle).
// Phase 2: K,V written to LDS in the (numerically verified) attn2 layouts; balanced
//   flash attention (each wave exactly 5 causal chunks); out stores.
// LDS union = 80 KB exactly: phase-1 {xs 32K | wts 12K} aliases phase-2 {Ks 32K | Vs 32K};
// Ps 16K is phase-2-only. Barriers protect every aliased transition.
// Traffic: x read once (402 MB) + out once (67 MB) — no Q/K/V image round-trip.
__global__ __launch_bounds__(512, 2) void fused_kernel(const float* __restrict__ x,
                                                       const unsigned short* __restrict__ Wt2,
                                                       float* __restrict__ out) {
    __shared__ __align__(16) unsigned short Ks[16384];   // 32 KB  (phase1: xs = x slice fp32)
    __shared__ __align__(16) unsigned short Vs[16384];   // 32 KB  (phase1: wts = weight slice)
    __shared__ __align__(16) unsigned short Ps[8192];    // 16 KB  per-wave scratch (Q conv + P)

    float*          xs  = (float*)Ks;                    // 256 rows x 32 floats, swizzled
    unsigned short* wts = Vs;                            // 6144 halfwords, swizzled

    const int tid  = threadIdx.x;
    const int lane = tid & 63;
    const int w    = tid >> 6;          // wave 0..7
    const int g    = lane >> 4;
    const int mr   = lane & 15;
    const int m7   = mr & 7;
    const int m3   = mr & 3;
    const int b    = blockIdx.x;
    const float* xb = x + (size_t)b * TT * EE;

    // -------- phase 1: QKV projection (rows = tiles w and 15-w) --------
    f32x4 acc[2][12];
#pragma unroll
    for (int ti = 0; ti < 2; ++ti)
#pragma unroll
        for (int nt = 0; nt < 12; ++nt) acc[ti][nt] = (f32x4){0.f, 0.f, 0.f, 0.f};

    const int swb   = (g ^ m3) << 3;    // B-frag swizzled chunk offset (halfwords)
    const int tileA = w;                // ti=0 rows
    const int tileB = 15 - w;           // ti=1 rows

    for (int kt = 0; kt < 12; ++kt) {
        // stage x slice: 256 rows x 32 floats (32 KB), 16B chunks permuted by c^(r&7)
#pragma unroll
        for (int j = 0; j < 4; ++j) {
            int chunk = j * 512 + tid;
            int r = chunk >> 3, c = chunk & 7;
            const float* src = xb + r * EE + kt * 32 + ((c ^ (r & 7)) << 2);
            gl_lds16(src, xs + (j * 512 + w * 64) * 4);
        }
        // stage weight slice: 768 chunks (12 KB), pre-swizzled in global
        {
            gl_lds16(Wt2 + kt * 6144 + tid * 8, wts + (w * 64) * 8);
        }
        if (tid < 256) {
            int ch = 512 + tid;
            gl_lds16(Wt2 + kt * 6144 + ch * 8, wts + (512 + w * 64) * 8);
        }
        __syncthreads();

        short8 afr[2];
#pragma unroll
        for (int ti = 0; ti < 2; ++ti) {
            const int lr = (ti ? tileB : tileA) * 16 + mr;
            const float* base = xs + lr * 32;
            f32x4 lo = *(const f32x4*)(base + (((2 * g)     ^ m7) << 2));
            f32x4 hi = *(const f32x4*)(base + (((2 * g + 1) ^ m7) << 2));
            union { short8 v; unsigned short u[8]; } cv;
            cv.u[0] = f2bf(lo.x); cv.u[1] = f2bf(lo.y); cv.u[2] = f2bf(lo.z); cv.u[3] = f2bf(lo.w);
            cv.u[4] = f2bf(hi.x); cv.u[5] = f2bf(hi.y); cv.u[6] = f2bf(hi.z); cv.u[7] = f2bf(hi.w);
            afr[ti] = cv.v;
        }
#pragma unroll
        for (int nt = 0; nt < 12; ++nt) {
            short8 bfr = *(const short8*)(wts + (nt * 16 + mr) * 32 + swb);
            acc[0][nt] = __builtin_amdgcn_mfma_f32_16x16x32_bf16(afr[0], bfr, acc[0][nt], 0, 0, 0);
            acc[1][nt] = __builtin_amdgcn_mfma_f32_16x16x32_bf16(afr[1], bfr, acc[1][nt], 0, 0, 0);
        }
        __syncthreads();   // WAR: next stage (or epilogue) overwrites xs/wts
    }

    // -------- epilogue: K,V -> LDS (attn2-verified layouts); Q -> register fragments --------
#pragma unroll
    for (int ti = 0; ti < 2; ++ti) {
        const int tbase = (ti ? tileB : tileA) * 16;
#pragma unroll
        for (int nt = 4; nt < 8; ++nt) {                 // K: Ks[t][hchunk ^ (t&7)]
            const int hc = (nt - 4) * 2 + (mr >> 3);
            f32x4 v = acc[ti][nt];
#pragma unroll
            for (int r = 0; r < 4; ++r) {
                const int t = tbase + g * 4 + r;
                Ks[t * 64 + ((hc ^ (t & 7)) << 3) + m7] = f2bf(v[r]);
            }
        }
#pragma unroll
        for (int nt = 8; nt < 12; ++nt) {                // V^T: Vs[h][tchunk ^ (h&7)]
            const int h  = (nt - 8) * 16 + mr;
            const int tq = tbase + g * 4;
            const int sw = (tq >> 3) ^ m7;
            f32x4 v = acc[ti][nt];
            us4 pk;
            pk.x = f2bf(v[0]); pk.y = f2bf(v[1]); pk.z = f2bf(v[2]); pk.w = f2bf(v[3]);
            *(us4*)(Vs + h * 256 + sw * 8 + (tq & 7)) = pk;
        }
    }

    // Q: C-layout -> A-fragment conversion through per-wave scratch (same swizzle pair
    // as the P path, which is numerically verified). Sequential reuse for the 2 tiles.
    unsigned short* pw = Ps + w * 1024;
    short8 qfr[2][2];
#pragma unroll
    for (int p = 0; p < 2; ++p) {
#pragma unroll
        for (int nt = 0; nt < 4; ++nt) {
            f32x4 v = acc[p][nt];
#pragma unroll
            for (int r = 0; r < 4; ++r) {
                const int lr = g * 4 + r;
                const int sw = (nt * 2 + (mr >> 3)) ^ (lr & 7);
                pw[lr * 64 + (sw << 3) + m7] = f2bf(v[r]);
            }
        }
#pragma unroll
        for (int kt = 0; kt < 2; ++kt)
            qfr[p][kt] = *(const short8*)(pw + mr * 64 + (((kt * 4 + g) ^ m7) << 3));
    }
    __syncthreads();   // K,V visible to all waves; Ps free for P-scratch reuse

    // -------- phase 2: balanced flash attention (tiles w, 15-w => 5 chunks/wave) --------
    const int swv0 = ((0 * 4 + g) ^ m7) << 3;
    const int swv1 = ((1 * 4 + g) ^ m7) << 3;

    short8 ones;
#pragma unroll
    for (int i = 0; i < 8; ++i) ones[i] = (short)0x3F80;   // bf16 1.0

#pragma unroll
    for (int p = 0; p < 2; ++p) {
        const int a   = p ? (15 - w) : w;
        const int r0  = a * 16;
        const int nch = (a >> 2) + 1;

        f32x4 o[4];
        f32x4 ls = (f32x4){0.f, 0.f, 0.f, 0.f};
        float mrun[4];
#pragma unroll
        for (int i = 0; i < 4; ++i) { o[i] = (f32x4){0.f, 0.f, 0.f, 0.f}; mrun[i] = -3.0e38f; }

        for (int j = 0; j < nch; ++j) {
            // S = Q K^T   (scale*log2e folded into Wq)
            f32x4 s[4];
#pragma unroll
            for (int nt = 0; nt < 4; ++nt) s[nt] = (f32x4){0.f, 0.f, 0.f, 0.f};
#pragma unroll
            for (int kt = 0; kt < 2; ++kt) {
                const short8 qf = qfr[p][kt];
                const int swv = kt ? swv1 : swv0;
#pragma unroll
                for (int nt = 0; nt < 4; ++nt) {
                    short8 kf = *(const short8*)(Ks + (j * 64 + nt * 16 + mr) * 64 + swv);
                    s[nt] = __builtin_amdgcn_mfma_f32_16x16x32_bf16(qf, kf, s[nt], 0, 0, 0);
                }
            }
            // causal mask: only the last chunk contains the diagonal
            if (j == nch - 1) {
#pragma unroll
                for (int nt = 0; nt < 4; ++nt) {
                    const int key = j * 64 + nt * 16 + mr;
#pragma unroll
                    for (int r = 0; r < 4; ++r)
                        if (key > r0 + g * 4 + r) s[nt][r] = -3.0e38f;
                }
            }
            // row max (4 regs + 16-lane shuffle tree)
            float cm[4], al[4];
#pragma unroll
            for (int r = 0; r < 4; ++r) {
                cm[r] = fmaxf(fmaxf(s[0][r], s[1][r]), fmaxf(s[2][r], s[3][r]));
                cm[r] = fmaxf(cm[r], __shfl_xor(cm[r], 1, 64));
                cm[r] = fmaxf(cm[r], __shfl_xor(cm[r], 2, 64));
                cm[r] = fmaxf(cm[r], __shfl_xor(cm[r], 4, 64));
                cm[r] = fmaxf(cm[r], __shfl_xor(cm[r], 8, 64));
                float mn = fmaxf(mrun[r], cm[r]);
                al[r] = exp2f(mrun[r] - mn);
                mrun[r] = mn;
            }
            // P = exp2(S - m) -> bf16 -> swizzled per-wave scratch
#pragma unroll
            for (int nt = 0; nt < 4; ++nt) {
#pragma unroll
                for (int r = 0; r < 4; ++r) {
                    const int lr = g * 4 + r;
                    const int sw = (nt * 2 + (mr >> 3)) ^ (lr & 7);
                    pw[lr * 64 + (sw << 3) + m7] = f2bf(exp2f(s[nt][r] - mrun[r]));
                }
            }
            // rescale, then O += P V and l += P*1 (ones-column MFMA)
#pragma unroll
            for (int hn = 0; hn < 4; ++hn)
#pragma unroll
                for (int r = 0; r < 4; ++r) o[hn][r] *= al[r];
#pragma unroll
            for (int r = 0; r < 4; ++r) ls[r] *= al[r];
#pragma unroll
            for (int kt = 0; kt < 2; ++kt) {
                const int swv = kt ? swv1 : swv0;
                short8 pf = *(const short8*)(pw + mr * 64 + swv);
#pragma unroll
                for (int hn = 0; hn < 4; ++hn) {
                    short8 vf = *(const short8*)(Vs + (hn * 16 + mr) * 256 + j * 64 + swv);
                    o[hn] = __builtin_amdgcn_mfma_f32_16x16x32_bf16(pf, vf, o[hn], 0, 0, 0);
                }
                ls = __builtin_amdgcn_mfma_f32_16x16x32_bf16(pf, ones, ls, 0, 0, 0);
            }
        }
        // normalize + store
        float* ob = out + ((size_t)b * TT + r0) * HH;
#pragma unroll
        for (int r = 0; r < 4; ++r) {
            const float inv = 1.0f / ls[r];
#pragma unroll
            for (int hn = 0; hn < 4; ++hn)
                ob[(g * 4 + r) * HH + hn * 16 + mr] = o[hn][r] * inv;
        }
    }
}

// ============================ launcher ============================

extern "C" void kernel_launch(void* const* d_in, const int* in_sizes, int n_in,
                              void* d_out, int out_size, void* d_ws, size_t ws_size,
                              hipStream_t stream) {
    const float* x  = (const float*)d_in[0];
    const float* Wq = (const float*)d_in[1];
    const float* Wk = (const float*)d_in[2];
    const float* Wv = (const float*)d_in[3];
    float* out = (float*)d_out;

    unsigned short* Wt2 = (unsigned short*)d_ws;        // 147456 B (proven to fit)
    prep2_kernel<<<288, 256, 0, stream>>>(Wq, Wk, Wv, Wt2);
    fused_kernel<<<BB, 512, 0, stream>>>(x, Wt2, out);
}